// Round 7
// baseline (610.827 us; speedup 1.0000x reference)
//
#include <hip/hip_runtime.h>
#include <math.h>

// Problem constants
constexpr int Bn  = 2;
constexpr int Sn  = 4096;
constexpr int En  = 1024;
constexpr int Hn  = 16;
constexpr int Mtot = Bn * Sn;             // 8192
constexpr int Kp  = 1024;                 // GEMM K (fp16 single precision)
constexpr int PAD = 72;                   // LDS row stride (bf16), 144 B = 9x16B

typedef __bf16    bf16x8 __attribute__((ext_vector_type(8)));
typedef __bf16    bf16x4 __attribute__((ext_vector_type(4)));
typedef _Float16  f16x8  __attribute__((ext_vector_type(8)));
typedef _Float16  f16x4  __attribute__((ext_vector_type(4)));
typedef float     f32x4  __attribute__((ext_vector_type(4)));

// ---------------- fp32 -> fp16 conversion (single fused dispatch) -----------
__global__ void __launch_bounds__(256)
cvt_all_kernel(const float* __restrict__ hs,
               const float* __restrict__ qw, const float* __restrict__ kw,
               const float* __restrict__ vw,
               _Float16* __restrict__ hs16, _Float16* __restrict__ w16)
{
    const int bid = blockIdx.x;
    if (bid < 8192) {
        int t = bid * 256 + threadIdx.x;
        int m = t >> 8;
        int k = (t & 255) << 2;
        float4 x = *(const float4*)&hs[((size_t)m << 10) + k];
        f16x4 h;
        h[0] = (_Float16)x.x; h[1] = (_Float16)x.y;
        h[2] = (_Float16)x.z; h[3] = (_Float16)x.w;
        *(f16x4*)&hs16[((size_t)m << 10) + k] = h;
    } else {
        int t = (bid - 8192) * 256 + threadIdx.x;
        int gn = t >> 8;
        int k  = (t & 255) << 2;
        int p  = gn >> 10, n = gn & 1023;
        const float* src = (p == 0) ? qw : (p == 1) ? kw : vw;
        float4 x = *(const float4*)&src[((size_t)n << 10) + k];
        f16x4 h;
        h[0] = (_Float16)x.x; h[1] = (_Float16)x.y;
        h[2] = (_Float16)x.z; h[3] = (_Float16)x.w;
        *(f16x4*)&w16[((size_t)gn << 10) + k] = h;
    }
}

// ---------------- QKV projection: 256x256-tile 8-wave MFMA GEMM -------------
// v8: occupancy-first rework of v7. r6 showed 1 block/CU (128KB LDS) executes
// 384 blocks as 2 sequential block-waves (2nd half-idle) with no co-residency
// to hide latency: 85us vs ~21us MFMA wall. Fix: drop the tile double-buffer
// and use the kc-halves as the two pipeline slots -> LDS 64KB -> 2 blocks/CU
// (384 blocks fit one execution wave of 512 slots; m114 wave-level overlap).
// Counted vmcnt retained (T4): per K-tile
//   stage kc1(kt) | vmcnt(4) retire kc0(kt) | bar | ds_read kc0 + 32 MFMA | bar
//   stage kc0(kt+1)| vmcnt(4) retire kc1(kt)| bar | ds_read kc1 + 32 MFMA | bar
// vmcnt(4) always leaves exactly the newest 4 loads (the other kc region);
// the only vmcnt(0) is the final tile's drain. Slot-overwrite races are
// barrier-protected: a slot's last ds_reads retire (lgkm before MFMA) before
// the barrier that precedes its re-stage.
// Retained: XOR bank swizzle (pre-swizzled global source), swapped-operand
// MFMA for q|k -> contiguous bf16x4 stores, fused q|k / v dispatch (uniform
// branch into disjoint template bodies).
__device__ inline void load_lds16(const void* g, void* s) {
    __builtin_amdgcn_global_load_lds((const __attribute__((address_space(1))) void*)g,
                                     (__attribute__((address_space(3))) void*)s,
                                     16, 0, 0);
}

__device__ inline void block_sync() {
    asm volatile("" ::: "memory");
    __builtin_amdgcn_s_barrier();
    asm volatile("" ::: "memory");
}
__device__ inline void vm_wait4() { asm volatile("s_waitcnt vmcnt(4)" ::: "memory"); }
__device__ inline void vm_wait0() { asm volatile("s_waitcnt vmcnt(0)" ::: "memory"); }

typedef _Float16 ldsAB_t[2][256][32];   // [kc][row][col] = 32 KiB per operand

template<int PM>   // 0 = q|k (swapped operands), 1 = v
__device__ __forceinline__ void
qkv_body(ldsAB_t& As, ldsAB_t& Bs,
         const _Float16* __restrict__ A2, const _Float16* __restrict__ B2,
         const float* __restrict__ qb, const float* __restrict__ kb,
         const float* __restrict__ vb,
         __bf16* __restrict__ q16, __bf16* __restrict__ k16,
         __bf16* __restrict__ vt16, int n0)
{
    const int tid  = threadIdx.x;
    const int w    = tid >> 6;             // 0..7
    const int lane = tid & 63;
    const int wm   = w >> 2, wn = w & 3;   // 2M x 4N wave grid
    const int mrow = lane & 15, quad = lane >> 4;
    const int m0   = blockIdx.x * 256;     // seq tile

    // staging: lane l -> LDS (row base + l>>2, slot l&3); global chunk =
    // (l&3) ^ ((l>>3)&3)  (inverse swizzle on the source, m173 pattern)
    const int subrow = lane >> 2;          // 0..15
    const int gch    = ((lane & 3) ^ ((lane >> 3) & 3)) * 8;   // f16 offset
    const _Float16* Ag = A2 + (size_t)(m0 + w * 32 + subrow) * Kp + gch;
    const _Float16* Bg = B2 + (size_t)(n0 + w * 32 + subrow) * Kp + gch;

    // frag read slot (f16 offset within the 32-col kc region)
    const int sl = (quad ^ ((mrow >> 1) & 3)) * 8;

    f32x4 acc[8][4] = {};

    auto stage = [&](int kt, int kc) {     // 4 vmcnt items per call
        const size_t goff = (size_t)kt * 64 + kc * 32;
#pragma unroll
        for (int l = 0; l < 2; l++)
            load_lds16(Ag + (size_t)l * 16 * Kp + goff, &As[kc][w * 32 + l * 16][0]);
#pragma unroll
        for (int l = 0; l < 2; l++)
            load_lds16(Bg + (size_t)l * 16 * Kp + goff, &Bs[kc][w * 32 + l * 16][0]);
    };
    auto ladder = [&](const f16x8* AF, const f16x8* BF, int r0) {
        __builtin_amdgcn_s_setprio(1);
#pragma unroll
        for (int ti = 0; ti < 4; ti++)
#pragma unroll
            for (int tj = 0; tj < 4; tj++) {
                if (PM == 0)   // C[m=feature][n=seq]
                    acc[r0 + ti][tj] = __builtin_amdgcn_mfma_f32_16x16x32_f16(
                        BF[tj], AF[ti], acc[r0 + ti][tj], 0, 0, 0);
                else           // C[m=seq][n=feature]
                    acc[r0 + ti][tj] = __builtin_amdgcn_mfma_f32_16x16x32_f16(
                        AF[ti], BF[tj], acc[r0 + ti][tj], 0, 0, 0);
            }
        __builtin_amdgcn_s_setprio(0);
    };

    constexpr int NT = Kp / 64;            // 16 K-tiles

    // Preload epilogue bias (older FIFO entries; retired by the first wait4).
    float4 bv4[4];      // PM0: float4 per tj     PM1: .x used per tj
    const int p = n0 >> 10;
    {
        const float* bptr = (p == 0) ? qb : (p == 1) ? kb : vb;
#pragma unroll
        for (int tj = 0; tj < 4; tj++) {
            if (PM == 0) {
                const int fl = (n0 + wn * 64 + tj * 16 + quad * 4) & 1023;
                bv4[tj] = *(const float4*)&bptr[fl];
            } else {
                const int n = (n0 + wn * 64 + tj * 16 + mrow) & 1023;
                bv4[tj].x = bptr[n];
            }
        }
    }

    // Prologue: kc0(0) in flight.
    stage(0, 0);

    for (int kt = 0; kt < NT; ++kt) {
        f16x8 af[4], bf[4];

        // ---- kc0 half: stage kc1(kt), retire kc0(kt), compute kc0 ----
        stage(kt, 1);
        vm_wait4();                        // retire bias(+) and kc0(kt)
        block_sync();
#pragma unroll
        for (int t = 0; t < 4; t++)
            af[t] = *(const f16x8*)&As[0][wm * 128 + t * 16 + mrow][sl];
#pragma unroll
        for (int t = 0; t < 4; t++)
            bf[t] = *(const f16x8*)&Bs[0][wn * 64 + t * 16 + mrow][sl];
        ladder(af, bf, 0);
#pragma unroll
        for (int t = 0; t < 4; t++)
            af[t] = *(const f16x8*)&As[0][wm * 128 + 64 + t * 16 + mrow][sl];
        ladder(af, bf, 4);
        block_sync();                      // kc0 reads retired before re-stage

        // ---- kc1 half: stage kc0(kt+1), retire kc1(kt), compute kc1 ----
        if (kt + 1 < NT) { stage(kt + 1, 0); vm_wait4(); }
        else             { vm_wait0(); }   // final drain (only vmcnt(0))
        block_sync();
#pragma unroll
        for (int t = 0; t < 4; t++)
            af[t] = *(const f16x8*)&As[1][wm * 128 + t * 16 + mrow][sl];
#pragma unroll
        for (int t = 0; t < 4; t++)
            bf[t] = *(const f16x8*)&Bs[1][wn * 64 + t * 16 + mrow][sl];
        ladder(af, bf, 0);
#pragma unroll
        for (int t = 0; t < 4; t++)
            af[t] = *(const f16x8*)&As[1][wm * 128 + 64 + t * 16 + mrow][sl];
        ladder(af, bf, 4);
        block_sync();                      // kc1 reads retired before re-stage
    }

    if (PM == 0) {
        // acc[ti][tj]: row (quad*4+r) = feature, col (mrow) = seq
        __bf16* dst = (p == 0) ? q16 : k16;
        const float scl = (p == 0) ? 0.125f : 1.0f;
#pragma unroll
        for (int ti = 0; ti < 8; ti++) {
            const int m  = m0 + wm * 128 + ti * 16 + mrow;   // seq
            const int bb = m >> 12, ss = m & 4095;
#pragma unroll
            for (int tj = 0; tj < 4; tj++) {
                const int fl = (n0 + wn * 64 + tj * 16 + quad * 4) & 1023;
                const int hh = fl >> 6, dd = fl & 63;        // dd..dd+3
                bf16x4 o;
                o[0] = (__bf16)((acc[ti][tj][0] + bv4[tj].x) * scl);
                o[1] = (__bf16)((acc[ti][tj][1] + bv4[tj].y) * scl);
                o[2] = (__bf16)((acc[ti][tj][2] + bv4[tj].z) * scl);
                o[3] = (__bf16)((acc[ti][tj][3] + bv4[tj].w) * scl);
                *(bf16x4*)&dst[((size_t)(bb * Hn + hh) * Sn + ss) * 64 + dd] = o;
            }
        }
    } else {
        // acc[ti][tj]: row (quad*4+r) = seq, col (mrow) = feature; V^T layout
#pragma unroll
        for (int tj = 0; tj < 4; tj++) {
            const int n  = n0 + wn * 64 + tj * 16 + mrow;
            const float bv = bv4[tj].x;
            const int hh = (n & 1023) >> 6, dd = n & 63;
#pragma unroll
            for (int ti = 0; ti < 8; ti++) {
                const int m  = m0 + wm * 128 + ti * 16 + quad * 4;   // + r
                const int bb = m >> 12, ss = m & 4095;
                bf16x4 pv4;
#pragma unroll
                for (int r = 0; r < 4; r++)
                    pv4[r] = (__bf16)(acc[ti][tj][r] + bv);
                *(bf16x4*)&vt16[((size_t)(bb * Hn + hh) * 64 + dd) * Sn + ss] = pv4;
            }
        }
    }
}

__global__ void __launch_bounds__(512, 4)
qkv_fused_kernel(const _Float16* __restrict__ A2, const _Float16* __restrict__ B2,
                 const float* __restrict__ qb, const float* __restrict__ kb,
                 const float* __restrict__ vb,
                 __bf16* __restrict__ q16, __bf16* __restrict__ k16,
                 __bf16* __restrict__ vt16)
{
    __shared__ ldsAB_t As, Bs;             // 64 KiB total -> 2 blocks/CU
    const int by = blockIdx.y;
    if (by < 8)
        qkv_body<0>(As, Bs, A2, B2, qb, kb, vb, q16, k16, vt16, by * 256);
    else
        qkv_body<1>(As, Bs, A2, B2, qb, kb, vb, q16, k16, vt16,
                    2048 + (by - 8) * 256);
}

// ---------------- Banded attention: MFMA, double-buffered staging -----------
// Block = 256 queries (4 waves x 64). S^T = K.Q^T ; O^T = V^T.P^T.
// v7 softmax-VALU cuts: (a) key-range validity folded into the Msh additive
// mask; (b) QK accumulator initialized with ms4 (MFMA C-in); (c) band check
// only on the two edge subtiles (wave-uniform branch).
__global__ void __launch_bounds__(256, 2)
banded_attn_kernel(const __bf16* __restrict__ q16, const __bf16* __restrict__ k16,
                   const __bf16* __restrict__ vt16, const int* __restrict__ mask,
                   float* __restrict__ out)
{
    __shared__ __bf16 Kt[2][64 * PAD];
    __shared__ __bf16 Vt[2][64 * PAD];
    __shared__ __bf16 Pt[4][64 * PAD];
    __shared__ float  Msh[768];

    const int c = blockIdx.x, h = blockIdx.y, b = blockIdx.z;
    const int bh = b * Hn + h;
    const int i0 = c * 256;
    const int jwin0 = i0 - 256;
    const int tid  = threadIdx.x;
    const int wv   = tid >> 6;
    const int lane = tid & 63;
    const int quad = lane >> 4, mrow = lane & 15;

#pragma unroll
    for (int rep = 0; rep < 3; rep++) {
        int idx = rep * 256 + tid;
        int jg  = jwin0 + idx;
        float mv = -10000.f;                     // out-of-range keys -> exp = 0
        if (jg >= 0 && jg < Sn)
            mv = (mask[b * Sn + jg] != 0) ? -10000.f : 0.f;
        Msh[idx] = mv;
    }

    // Q B-fragments (loop-invariant): B[k=d][n=q]
    bf16x8 qf[4][2];
    const __bf16* qbase = q16 + (((size_t)bh * Sn + i0 + wv * 64) << 6);
#pragma unroll
    for (int tjq = 0; tjq < 4; tjq++)
#pragma unroll
        for (int kc = 0; kc < 2; kc++)
            qf[tjq][kc] = *(const bf16x8*)(qbase + (16 * tjq + mrow) * 64 + 32 * kc + 8 * quad);

    const int sr = lane >> 3;      // 0..7
    const int sc = lane & 7;       // 16B chunk
    bf16x8 kreg0, kreg1, vreg0, vreg1;
    auto gload = [&](int st) {
        const int j0 = jwin0 + st * 64;
        const int r0 = wv * 16 + sr;
        const int r1 = wv * 16 + 8 + sr;
        int jk0 = j0 + r0; jk0 = jk0 < 0 ? 0 : (jk0 > Sn - 1 ? Sn - 1 : jk0);
        int jk1 = j0 + r1; jk1 = jk1 < 0 ? 0 : (jk1 > Sn - 1 ? Sn - 1 : jk1);
        kreg0 = *(const bf16x8*)&k16[(((size_t)bh * Sn + jk0) << 6) + sc * 8];
        kreg1 = *(const bf16x8*)&k16[(((size_t)bh * Sn + jk1) << 6) + sc * 8];
        int jv = j0 + sc * 8; jv = jv < 0 ? 0 : (jv > Sn - 8 ? Sn - 8 : jv);
        vreg0 = *(const bf16x8*)&vt16[((size_t)bh * 64 + r0) * Sn + jv];
        vreg1 = *(const bf16x8*)&vt16[((size_t)bh * 64 + r1) * Sn + jv];
    };
    auto swrite = [&](int buf) {
        *(bf16x8*)&Kt[buf][(wv * 16 + sr) * PAD + sc * 8]     = kreg0;
        *(bf16x8*)&Kt[buf][(wv * 16 + 8 + sr) * PAD + sc * 8] = kreg1;
        *(bf16x8*)&Vt[buf][(wv * 16 + sr) * PAD + sc * 8]     = vreg0;
        *(bf16x8*)&Vt[buf][(wv * 16 + 8 + sr) * PAD + sc * 8] = vreg1;
    };

    f32x4 acc_o[4][4] = {};
    float lrun[4] = {0.f, 0.f, 0.f, 0.f};
    __bf16* Pw = &Pt[wv][0];

    gload(0);
    swrite(0);
    __syncthreads();

    for (int st = 0; st < 12; st++) {
        const int buf = st & 1;
        if (st + 1 < 12) gload(st + 1);   // issue next global loads early

        if (st >= wv && st <= wv + 8) {
            const __bf16* KtB = &Kt[buf][0];
            const __bf16* VtB = &Vt[buf][0];
            const bool edge = (st == wv) || (st == wv + 8);
            // ---- S^T = K.Q^T, softmax, P -> LDS [query][key] ----
#pragma unroll
            for (int ti = 0; ti < 4; ti++) {
                bf16x8 ak0 = *(const bf16x8*)&KtB[(16 * ti + mrow) * PAD + quad * 8];
                bf16x8 ak1 = *(const bf16x8*)&KtB[(16 * ti + mrow) * PAD + 32 + quad * 8];
                const int y0 = 64 * st + 16 * ti + 4 * quad;
                const f32x4 ms4 = *(const f32x4*)&Msh[y0];
#pragma unroll
                for (int tjq = 0; tjq < 4; tjq++) {
                    f32x4 s = ms4;    // additive mask as MFMA C-in
                    s = __builtin_amdgcn_mfma_f32_16x16x32_bf16(ak0, qf[tjq][0], s, 0, 0, 0);
                    s = __builtin_amdgcn_mfma_f32_16x16x32_bf16(ak1, qf[tjq][1], s, 0, 0, 0);
                    bf16x4 pk;
                    float psum = 0.f;
                    if (edge) {
                        const int xq = 64 * wv + 16 * tjq + mrow;
#pragma unroll
                        for (int r = 0; r < 4; r++) {
                            bool ok = ((unsigned)(y0 + r - xq) <= 512u);
                            float pv = ok ? __expf(s[r]) : 0.f;
                            psum += pv;
                            pk[r] = (__bf16)pv;
                        }
                    } else {
                        // interior subtile: band always satisfied, bounds in Msh
#pragma unroll
                        for (int r = 0; r < 4; r++) {
                            float pv = __expf(s[r]);
                            psum += pv;
                            pk[r] = (__bf16)pv;
                        }
                    }
                    lrun[tjq] += psum;
                    *(bf16x4*)&Pw[(16 * tjq + mrow) * PAD + 16 * ti + 4 * quad] = pk;
                }
            }
            // ---- O^T += V^T.P^T ----
#pragma unroll
            for (int kc2 = 0; kc2 < 2; kc2++) {
                bf16x8 av[4];
#pragma unroll
                for (int dt = 0; dt < 4; dt++)
                    av[dt] = *(const bf16x8*)&VtB[(16 * dt + mrow) * PAD + kc2 * 32 + quad * 8];
#pragma unroll
                for (int tjq = 0; tjq < 4; tjq++) {
                    bf16x8 pf = *(const bf16x8*)&Pw[(16 * tjq + mrow) * PAD + kc2 * 32 + quad * 8];
#pragma unroll
                    for (int dt = 0; dt < 4; dt++)
                        acc_o[dt][tjq] = __builtin_amdgcn_mfma_f32_16x16x32_bf16(
                            av[dt], pf, acc_o[dt][tjq], 0, 0, 0);
                }
            }
        }

        if (st + 1 < 12) {
            swrite((st + 1) & 1);
            __syncthreads();
        }
    }

    // denominators: sum across quads (keys live across lane bits 4-5)
    float inv[4];
#pragma unroll
    for (int tjq = 0; tjq < 4; tjq++) {
        float l = lrun[tjq];
        l += __shfl_xor(l, 16);
        l += __shfl_xor(l, 32);
        inv[tjq] = 1.0f / l;
    }
    // O^T C-layout: row = d = 16*dt + 4*quad + r, col = q = mrow
#pragma unroll
    for (int dt = 0; dt < 4; dt++)
#pragma unroll
        for (int tjq = 0; tjq < 4; tjq++) {
            f32x4 o = acc_o[dt][tjq];
            o[0] *= inv[tjq]; o[1] *= inv[tjq]; o[2] *= inv[tjq]; o[3] *= inv[tjq];
            float* dst = out + ((size_t)(b * Sn + i0 + wv * 64 + 16 * tjq + mrow)) * En
                             + h * 64 + 16 * dt + 4 * quad;
            *(f32x4*)dst = o;
        }
}

extern "C" void kernel_launch(void* const* d_in, const int* in_sizes, int n_in,
                              void* d_out, int out_size, void* d_ws, size_t ws_size,
                              hipStream_t stream) {
    const float* hs  = (const float*)d_in[0];
    const int*  mask = (const int*)d_in[1];
    const float* qw  = (const float*)d_in[2];
    const float* qb  = (const float*)d_in[3];
    const float* kw  = (const float*)d_in[4];
    const float* kb  = (const float*)d_in[5];
    const float* vw  = (const float*)d_in[6];
    const float* vb  = (const float*)d_in[7];
    float* out = (float*)d_out;

    // Workspace: hs16 16.8MB | w16 6.3MB | q16 16.8MB | k16 16.8MB | vt16 16.8MB
    _Float16* hs16 = (_Float16*)d_ws;
    _Float16* w16  = (_Float16*)((char*)d_ws + (size_t)16777216);
    __bf16*   q16  = (__bf16*)((char*)d_ws + (size_t)23068672);
    __bf16*   k16  = (__bf16*)((char*)d_ws + (size_t)39845888);
    __bf16*   vt16 = (__bf16*)((char*)d_ws + (size_t)56623104);

    cvt_all_kernel<<<8192 + 3072, 256, 0, stream>>>(hs, qw, kw, vw, hs16, w16);

    dim3 pgrid(Mtot / 256, 12);             // (32, 12): y<8 = q|k, y>=8 = v
    qkv_fused_kernel<<<pgrid, 512, 0, stream>>>(hs16, w16, qb, kb, vb,
                                                q16, k16, vt16);

    dim3 agrid(Sn / 256, Hn, Bn);           // (16, 16, 2)
    banded_attn_kernel<<<agrid, 256, 0, stream>>>(q16, k16, vt16, mask, out);
}

// Round 8
// 227.340 us; speedup vs baseline: 2.6868x; 2.6868x over previous
//
#include <hip/hip_runtime.h>
#include <math.h>

// Problem constants
constexpr int Bn  = 2;
constexpr int Sn  = 4096;
constexpr int En  = 1024;
constexpr int Hn  = 16;
constexpr int Mtot = Bn * Sn;             // 8192
constexpr int Kp  = 1024;                 // GEMM K (fp16 single precision)
constexpr int PAD = 72;                   // LDS row stride (bf16), 144 B = 9x16B

typedef __bf16    bf16x8 __attribute__((ext_vector_type(8)));
typedef __bf16    bf16x4 __attribute__((ext_vector_type(4)));
typedef _Float16  f16x8  __attribute__((ext_vector_type(8)));
typedef _Float16  f16x4  __attribute__((ext_vector_type(4)));
typedef float     f32x4  __attribute__((ext_vector_type(4)));

// ---------------- fp32 -> fp16 conversion (single fused dispatch) -----------
__global__ void __launch_bounds__(256)
cvt_all_kernel(const float* __restrict__ hs,
               const float* __restrict__ qw, const float* __restrict__ kw,
               const float* __restrict__ vw,
               _Float16* __restrict__ hs16, _Float16* __restrict__ w16)
{
    const int bid = blockIdx.x;
    if (bid < 8192) {
        int t = bid * 256 + threadIdx.x;
        int m = t >> 8;
        int k = (t & 255) << 2;
        float4 x = *(const float4*)&hs[((size_t)m << 10) + k];
        f16x4 h;
        h[0] = (_Float16)x.x; h[1] = (_Float16)x.y;
        h[2] = (_Float16)x.z; h[3] = (_Float16)x.w;
        *(f16x4*)&hs16[((size_t)m << 10) + k] = h;
    } else {
        int t = (bid - 8192) * 256 + threadIdx.x;
        int gn = t >> 8;
        int k  = (t & 255) << 2;
        int p  = gn >> 10, n = gn & 1023;
        const float* src = (p == 0) ? qw : (p == 1) ? kw : vw;
        float4 x = *(const float4*)&src[((size_t)n << 10) + k];
        f16x4 h;
        h[0] = (_Float16)x.x; h[1] = (_Float16)x.y;
        h[2] = (_Float16)x.z; h[3] = (_Float16)x.w;
        *(f16x4*)&w16[((size_t)gn << 10) + k] = h;
    }
}

// ---------------- QKV projection: 256x256-tile 8-wave MFMA GEMM -------------
// v9 = v8 with the launch_bounds regression fixed.
// r7 post-mortem: __launch_bounds__(512,4) capped VGPR at 64 -> the 128-reg
// accumulator spilled to scratch (FETCH 725MB, WRITE 1.3GB, MfmaUtil 0.25%,
// 484us). (512,2) compiles the same body to ~116 VGPR with no spill; since
// 116 <= 128 the HW can still co-schedule 2 blocks/CU at 64KB LDS -- the
// occupancy comes from resources, not the bound.
// Structure (from v8): single-buffer 64KB LDS, kc-halves as pipeline slots,
// counted vmcnt (T4) -- per K-tile:
//   stage kc1(kt) | vmcnt(4) retire kc0(kt) | bar | ds_read kc0 + 32 MFMA | bar
//   stage kc0(kt+1)| vmcnt(4) retire kc1(kt)| bar | ds_read kc1 + 32 MFMA | bar
// Only vmcnt(0) is the final drain. XOR bank swizzle on pre-swizzled global
// source; swapped-operand MFMA for q|k -> contiguous bf16x4 stores; fused
// q|k / v dispatch (uniform branch into disjoint template bodies).
__device__ inline void load_lds16(const void* g, void* s) {
    __builtin_amdgcn_global_load_lds((const __attribute__((address_space(1))) void*)g,
                                     (__attribute__((address_space(3))) void*)s,
                                     16, 0, 0);
}

__device__ inline void block_sync() {
    asm volatile("" ::: "memory");
    __builtin_amdgcn_s_barrier();
    asm volatile("" ::: "memory");
}
__device__ inline void vm_wait4() { asm volatile("s_waitcnt vmcnt(4)" ::: "memory"); }
__device__ inline void vm_wait0() { asm volatile("s_waitcnt vmcnt(0)" ::: "memory"); }

typedef _Float16 ldsAB_t[2][256][32];   // [kc][row][col] = 32 KiB per operand

template<int PM>   // 0 = q|k (swapped operands), 1 = v
__device__ __forceinline__ void
qkv_body(ldsAB_t& As, ldsAB_t& Bs,
         const _Float16* __restrict__ A2, const _Float16* __restrict__ B2,
         const float* __restrict__ qb, const float* __restrict__ kb,
         const float* __restrict__ vb,
         __bf16* __restrict__ q16, __bf16* __restrict__ k16,
         __bf16* __restrict__ vt16, int n0)
{
    const int tid  = threadIdx.x;
    const int w    = tid >> 6;             // 0..7
    const int lane = tid & 63;
    const int wm   = w >> 2, wn = w & 3;   // 2M x 4N wave grid
    const int mrow = lane & 15, quad = lane >> 4;
    const int m0   = blockIdx.x * 256;     // seq tile

    // staging: lane l -> LDS (row base + l>>2, slot l&3); global chunk =
    // (l&3) ^ ((l>>3)&3)  (inverse swizzle on the source, m173 pattern)
    const int subrow = lane >> 2;          // 0..15
    const int gch    = ((lane & 3) ^ ((lane >> 3) & 3)) * 8;   // f16 offset
    const _Float16* Ag = A2 + (size_t)(m0 + w * 32 + subrow) * Kp + gch;
    const _Float16* Bg = B2 + (size_t)(n0 + w * 32 + subrow) * Kp + gch;

    // frag read slot (f16 offset within the 32-col kc region)
    const int sl = (quad ^ ((mrow >> 1) & 3)) * 8;

    f32x4 acc[8][4] = {};

    auto stage = [&](int kt, int kc) {     // 4 vmcnt items per call
        const size_t goff = (size_t)kt * 64 + kc * 32;
#pragma unroll
        for (int l = 0; l < 2; l++)
            load_lds16(Ag + (size_t)l * 16 * Kp + goff, &As[kc][w * 32 + l * 16][0]);
#pragma unroll
        for (int l = 0; l < 2; l++)
            load_lds16(Bg + (size_t)l * 16 * Kp + goff, &Bs[kc][w * 32 + l * 16][0]);
    };
    auto ladder = [&](const f16x8* AF, const f16x8* BF, int r0) {
        __builtin_amdgcn_s_setprio(1);
#pragma unroll
        for (int ti = 0; ti < 4; ti++)
#pragma unroll
            for (int tj = 0; tj < 4; tj++) {
                if (PM == 0)   // C[m=feature][n=seq]
                    acc[r0 + ti][tj] = __builtin_amdgcn_mfma_f32_16x16x32_f16(
                        BF[tj], AF[ti], acc[r0 + ti][tj], 0, 0, 0);
                else           // C[m=seq][n=feature]
                    acc[r0 + ti][tj] = __builtin_amdgcn_mfma_f32_16x16x32_f16(
                        AF[ti], BF[tj], acc[r0 + ti][tj], 0, 0, 0);
            }
        __builtin_amdgcn_s_setprio(0);
    };

    constexpr int NT = Kp / 64;            // 16 K-tiles

    // Preload epilogue bias (older FIFO entries; retired by the first wait4).
    float4 bv4[4];      // PM0: float4 per tj     PM1: .x used per tj
    const int p = n0 >> 10;
    {
        const float* bptr = (p == 0) ? qb : (p == 1) ? kb : vb;
#pragma unroll
        for (int tj = 0; tj < 4; tj++) {
            if (PM == 0) {
                const int fl = (n0 + wn * 64 + tj * 16 + quad * 4) & 1023;
                bv4[tj] = *(const float4*)&bptr[fl];
            } else {
                const int n = (n0 + wn * 64 + tj * 16 + mrow) & 1023;
                bv4[tj].x = bptr[n];
            }
        }
    }

    // Prologue: kc0(0) in flight.
    stage(0, 0);

    for (int kt = 0; kt < NT; ++kt) {
        f16x8 af[4], bf[4];

        // ---- kc0 half: stage kc1(kt), retire kc0(kt), compute kc0 ----
        stage(kt, 1);
        vm_wait4();                        // retire bias(+) and kc0(kt)
        block_sync();
#pragma unroll
        for (int t = 0; t < 4; t++)
            af[t] = *(const f16x8*)&As[0][wm * 128 + t * 16 + mrow][sl];
#pragma unroll
        for (int t = 0; t < 4; t++)
            bf[t] = *(const f16x8*)&Bs[0][wn * 64 + t * 16 + mrow][sl];
        ladder(af, bf, 0);
#pragma unroll
        for (int t = 0; t < 4; t++)
            af[t] = *(const f16x8*)&As[0][wm * 128 + 64 + t * 16 + mrow][sl];
        ladder(af, bf, 4);
        block_sync();                      // kc0 reads retired before re-stage

        // ---- kc1 half: stage kc0(kt+1), retire kc1(kt), compute kc1 ----
        if (kt + 1 < NT) { stage(kt + 1, 0); vm_wait4(); }
        else             { vm_wait0(); }   // final drain (only vmcnt(0))
        block_sync();
#pragma unroll
        for (int t = 0; t < 4; t++)
            af[t] = *(const f16x8*)&As[1][wm * 128 + t * 16 + mrow][sl];
#pragma unroll
        for (int t = 0; t < 4; t++)
            bf[t] = *(const f16x8*)&Bs[1][wn * 64 + t * 16 + mrow][sl];
        ladder(af, bf, 0);
#pragma unroll
        for (int t = 0; t < 4; t++)
            af[t] = *(const f16x8*)&As[1][wm * 128 + 64 + t * 16 + mrow][sl];
        ladder(af, bf, 4);
        block_sync();                      // kc1 reads retired before re-stage
    }

    if (PM == 0) {
        // acc[ti][tj]: row (quad*4+r) = feature, col (mrow) = seq
        __bf16* dst = (p == 0) ? q16 : k16;
        const float scl = (p == 0) ? 0.125f : 1.0f;
#pragma unroll
        for (int ti = 0; ti < 8; ti++) {
            const int m  = m0 + wm * 128 + ti * 16 + mrow;   // seq
            const int bb = m >> 12, ss = m & 4095;
#pragma unroll
            for (int tj = 0; tj < 4; tj++) {
                const int fl = (n0 + wn * 64 + tj * 16 + quad * 4) & 1023;
                const int hh = fl >> 6, dd = fl & 63;        // dd..dd+3
                bf16x4 o;
                o[0] = (__bf16)((acc[ti][tj][0] + bv4[tj].x) * scl);
                o[1] = (__bf16)((acc[ti][tj][1] + bv4[tj].y) * scl);
                o[2] = (__bf16)((acc[ti][tj][2] + bv4[tj].z) * scl);
                o[3] = (__bf16)((acc[ti][tj][3] + bv4[tj].w) * scl);
                *(bf16x4*)&dst[((size_t)(bb * Hn + hh) * Sn + ss) * 64 + dd] = o;
            }
        }
    } else {
        // acc[ti][tj]: row (quad*4+r) = seq, col (mrow) = feature; V^T layout
#pragma unroll
        for (int tj = 0; tj < 4; tj++) {
            const int n  = n0 + wn * 64 + tj * 16 + mrow;
            const float bv = bv4[tj].x;
            const int hh = (n & 1023) >> 6, dd = n & 63;
#pragma unroll
            for (int ti = 0; ti < 8; ti++) {
                const int m  = m0 + wm * 128 + ti * 16 + quad * 4;   // + r
                const int bb = m >> 12, ss = m & 4095;
                bf16x4 pv4;
#pragma unroll
                for (int r = 0; r < 4; r++)
                    pv4[r] = (__bf16)(acc[ti][tj][r] + bv);
                *(bf16x4*)&vt16[((size_t)(bb * Hn + hh) * 64 + dd) * Sn + ss] = pv4;
            }
        }
    }
}

__global__ void __launch_bounds__(512, 2)
qkv_fused_kernel(const _Float16* __restrict__ A2, const _Float16* __restrict__ B2,
                 const float* __restrict__ qb, const float* __restrict__ kb,
                 const float* __restrict__ vb,
                 __bf16* __restrict__ q16, __bf16* __restrict__ k16,
                 __bf16* __restrict__ vt16)
{
    __shared__ ldsAB_t As, Bs;             // 64 KiB total -> 2 blocks/CU
    const int by = blockIdx.y;
    if (by < 8)
        qkv_body<0>(As, Bs, A2, B2, qb, kb, vb, q16, k16, vt16, by * 256);
    else
        qkv_body<1>(As, Bs, A2, B2, qb, kb, vb, q16, k16, vt16,
                    2048 + (by - 8) * 256);
}

// ---------------- Banded attention: MFMA, double-buffered staging -----------
// Block = 256 queries (4 waves x 64). S^T = K.Q^T ; O^T = V^T.P^T.
// v7 softmax-VALU cuts: (a) key-range validity folded into the Msh additive
// mask; (b) QK accumulator initialized with ms4 (MFMA C-in); (c) band check
// only on the two edge subtiles (wave-uniform branch).
__global__ void __launch_bounds__(256, 2)
banded_attn_kernel(const __bf16* __restrict__ q16, const __bf16* __restrict__ k16,
                   const __bf16* __restrict__ vt16, const int* __restrict__ mask,
                   float* __restrict__ out)
{
    __shared__ __bf16 Kt[2][64 * PAD];
    __shared__ __bf16 Vt[2][64 * PAD];
    __shared__ __bf16 Pt[4][64 * PAD];
    __shared__ float  Msh[768];

    const int c = blockIdx.x, h = blockIdx.y, b = blockIdx.z;
    const int bh = b * Hn + h;
    const int i0 = c * 256;
    const int jwin0 = i0 - 256;
    const int tid  = threadIdx.x;
    const int wv   = tid >> 6;
    const int lane = tid & 63;
    const int quad = lane >> 4, mrow = lane & 15;

#pragma unroll
    for (int rep = 0; rep < 3; rep++) {
        int idx = rep * 256 + tid;
        int jg  = jwin0 + idx;
        float mv = -10000.f;                     // out-of-range keys -> exp = 0
        if (jg >= 0 && jg < Sn)
            mv = (mask[b * Sn + jg] != 0) ? -10000.f : 0.f;
        Msh[idx] = mv;
    }

    // Q B-fragments (loop-invariant): B[k=d][n=q]
    bf16x8 qf[4][2];
    const __bf16* qbase = q16 + (((size_t)bh * Sn + i0 + wv * 64) << 6);
#pragma unroll
    for (int tjq = 0; tjq < 4; tjq++)
#pragma unroll
        for (int kc = 0; kc < 2; kc++)
            qf[tjq][kc] = *(const bf16x8*)(qbase + (16 * tjq + mrow) * 64 + 32 * kc + 8 * quad);

    const int sr = lane >> 3;      // 0..7
    const int sc = lane & 7;       // 16B chunk
    bf16x8 kreg0, kreg1, vreg0, vreg1;
    auto gload = [&](int st) {
        const int j0 = jwin0 + st * 64;
        const int r0 = wv * 16 + sr;
        const int r1 = wv * 16 + 8 + sr;
        int jk0 = j0 + r0; jk0 = jk0 < 0 ? 0 : (jk0 > Sn - 1 ? Sn - 1 : jk0);
        int jk1 = j0 + r1; jk1 = jk1 < 0 ? 0 : (jk1 > Sn - 1 ? Sn - 1 : jk1);
        kreg0 = *(const bf16x8*)&k16[(((size_t)bh * Sn + jk0) << 6) + sc * 8];
        kreg1 = *(const bf16x8*)&k16[(((size_t)bh * Sn + jk1) << 6) + sc * 8];
        int jv = j0 + sc * 8; jv = jv < 0 ? 0 : (jv > Sn - 8 ? Sn - 8 : jv);
        vreg0 = *(const bf16x8*)&vt16[((size_t)bh * 64 + r0) * Sn + jv];
        vreg1 = *(const bf16x8*)&vt16[((size_t)bh * 64 + r1) * Sn + jv];
    };
    auto swrite = [&](int buf) {
        *(bf16x8*)&Kt[buf][(wv * 16 + sr) * PAD + sc * 8]     = kreg0;
        *(bf16x8*)&Kt[buf][(wv * 16 + 8 + sr) * PAD + sc * 8] = kreg1;
        *(bf16x8*)&Vt[buf][(wv * 16 + sr) * PAD + sc * 8]     = vreg0;
        *(bf16x8*)&Vt[buf][(wv * 16 + 8 + sr) * PAD + sc * 8] = vreg1;
    };

    f32x4 acc_o[4][4] = {};
    float lrun[4] = {0.f, 0.f, 0.f, 0.f};
    __bf16* Pw = &Pt[wv][0];

    gload(0);
    swrite(0);
    __syncthreads();

    for (int st = 0; st < 12; st++) {
        const int buf = st & 1;
        if (st + 1 < 12) gload(st + 1);   // issue next global loads early

        if (st >= wv && st <= wv + 8) {
            const __bf16* KtB = &Kt[buf][0];
            const __bf16* VtB = &Vt[buf][0];
            const bool edge = (st == wv) || (st == wv + 8);
            // ---- S^T = K.Q^T, softmax, P -> LDS [query][key] ----
#pragma unroll
            for (int ti = 0; ti < 4; ti++) {
                bf16x8 ak0 = *(const bf16x8*)&KtB[(16 * ti + mrow) * PAD + quad * 8];
                bf16x8 ak1 = *(const bf16x8*)&KtB[(16 * ti + mrow) * PAD + 32 + quad * 8];
                const int y0 = 64 * st + 16 * ti + 4 * quad;
                const f32x4 ms4 = *(const f32x4*)&Msh[y0];
#pragma unroll
                for (int tjq = 0; tjq < 4; tjq++) {
                    f32x4 s = ms4;    // additive mask as MFMA C-in
                    s = __builtin_amdgcn_mfma_f32_16x16x32_bf16(ak0, qf[tjq][0], s, 0, 0, 0);
                    s = __builtin_amdgcn_mfma_f32_16x16x32_bf16(ak1, qf[tjq][1], s, 0, 0, 0);
                    bf16x4 pk;
                    float psum = 0.f;
                    if (edge) {
                        const int xq = 64 * wv + 16 * tjq + mrow;
#pragma unroll
                        for (int r = 0; r < 4; r++) {
                            bool ok = ((unsigned)(y0 + r - xq) <= 512u);
                            float pv = ok ? __expf(s[r]) : 0.f;
                            psum += pv;
                            pk[r] = (__bf16)pv;
                        }
                    } else {
                        // interior subtile: band always satisfied, bounds in Msh
#pragma unroll
                        for (int r = 0; r < 4; r++) {
                            float pv = __expf(s[r]);
                            psum += pv;
                            pk[r] = (__bf16)pv;
                        }
                    }
                    lrun[tjq] += psum;
                    *(bf16x4*)&Pw[(16 * tjq + mrow) * PAD + 16 * ti + 4 * quad] = pk;
                }
            }
            // ---- O^T += V^T.P^T ----
#pragma unroll
            for (int kc2 = 0; kc2 < 2; kc2++) {
                bf16x8 av[4];
#pragma unroll
                for (int dt = 0; dt < 4; dt++)
                    av[dt] = *(const bf16x8*)&VtB[(16 * dt + mrow) * PAD + kc2 * 32 + quad * 8];
#pragma unroll
                for (int tjq = 0; tjq < 4; tjq++) {
                    bf16x8 pf = *(const bf16x8*)&Pw[(16 * tjq + mrow) * PAD + kc2 * 32 + quad * 8];
#pragma unroll
                    for (int dt = 0; dt < 4; dt++)
                        acc_o[dt][tjq] = __builtin_amdgcn_mfma_f32_16x16x32_bf16(
                            av[dt], pf, acc_o[dt][tjq], 0, 0, 0);
                }
            }
        }

        if (st + 1 < 12) {
            swrite((st + 1) & 1);
            __syncthreads();
        }
    }

    // denominators: sum across quads (keys live across lane bits 4-5)
    float inv[4];
#pragma unroll
    for (int tjq = 0; tjq < 4; tjq++) {
        float l = lrun[tjq];
        l += __shfl_xor(l, 16);
        l += __shfl_xor(l, 32);
        inv[tjq] = 1.0f / l;
    }
    // O^T C-layout: row = d = 16*dt + 4*quad + r, col = q = mrow
#pragma unroll
    for (int dt = 0; dt < 4; dt++)
#pragma unroll
        for (int tjq = 0; tjq < 4; tjq++) {
            f32x4 o = acc_o[dt][tjq];
            o[0] *= inv[tjq]; o[1] *= inv[tjq]; o[2] *= inv[tjq]; o[3] *= inv[tjq];
            float* dst = out + ((size_t)(b * Sn + i0 + wv * 64 + 16 * tjq + mrow)) * En
                             + h * 64 + 16 * dt + 4 * quad;
            *(f32x4*)dst = o;
        }
}

extern "C" void kernel_launch(void* const* d_in, const int* in_sizes, int n_in,
                              void* d_out, int out_size, void* d_ws, size_t ws_size,
                              hipStream_t stream) {
    const float* hs  = (const float*)d_in[0];
    const int*  mask = (const int*)d_in[1];
    const float* qw  = (const float*)d_in[2];
    const float* qb  = (const float*)d_in[3];
    const float* kw  = (const float*)d_in[4];
    const float* kb  = (const float*)d_in[5];
    const float* vw  = (const float*)d_in[6];
    const float* vb  = (const float*)d_in[7];
    float* out = (float*)d_out;

    // Workspace: hs16 16.8MB | w16 6.3MB | q16 16.8MB | k16 16.8MB | vt16 16.8MB
    _Float16* hs16 = (_Float16*)d_ws;
    _Float16* w16  = (_Float16*)((char*)d_ws + (size_t)16777216);
    __bf16*   q16  = (__bf16*)((char*)d_ws + (size_t)23068672);
    __bf16*   k16  = (__bf16*)((char*)d_ws + (size_t)39845888);
    __bf16*   vt16 = (__bf16*)((char*)d_ws + (size_t)56623104);

    cvt_all_kernel<<<8192 + 3072, 256, 0, stream>>>(hs, qw, kw, vw, hs16, w16);

    dim3 pgrid(Mtot / 256, 12);             // (32, 12): y<8 = q|k, y>=8 = v
    qkv_fused_kernel<<<pgrid, 512, 0, stream>>>(hs16, w16, qb, kb, vb,
                                                q16, k16, vt16);

    dim3 agrid(Sn / 256, Hn, Bn);           // (16, 16, 2)
    banded_attn_kernel<<<agrid, 256, 0, stream>>>(q16, k16, vt16, mask, out);
}